// Round 17
// baseline (128.484 us; speedup 1.0000x reference)
//
#include <hip/hip_runtime.h>
#include <math.h>
#include <utility>

#define BATCH 16384
#define INPUT_DIM 512
#define HIDDEN 1024
#define NROT 32
#define NANG 496   // 32*31/2

typedef _Float16 half8 __attribute__((ext_vector_type(8)));
typedef _Float16 half4 __attribute__((ext_vector_type(4)));
typedef float    f32x4 __attribute__((ext_vector_type(4)));

// ---------------------------------------------------------------------------
// f32 -> f16 conversion (prep pass), 8 elems/thread
// ---------------------------------------------------------------------------
__global__ __launch_bounds__(256) void cvt_f32_f16(
    const float* __restrict__ src, _Float16* __restrict__ dst, int n8)
{
    const int i = blockIdx.x * 256 + threadIdx.x;
    if (i < n8) {
        const float4* s = (const float4*)src + (size_t)i * 2;
        const float4 a = s[0], b = s[1];
        half8 h;
        h[0]=(_Float16)a.x; h[1]=(_Float16)a.y; h[2]=(_Float16)a.z; h[3]=(_Float16)a.w;
        h[4]=(_Float16)b.x; h[5]=(_Float16)b.y; h[6]=(_Float16)b.z; h[7]=(_Float16)b.w;
        *(half8*)(dst + (size_t)i * 8) = h;
    }
}

// ---------------------------------------------------------------------------
// Single-pass f16 MFMA GEMM (NT): C = epi(A[M,K] @ B[N,K]^T + bias)
//   EPI=0: relu -> f16 Ch[M][Nout]
//   EPI=1: theta -> f32 Cf[M][Nout]
// (unchanged from round 15)
// ---------------------------------------------------------------------------
template<int EPI>
__global__ __launch_bounds__(256) void gemm_nt_f16(
    const _Float16* __restrict__ A, const _Float16* __restrict__ B,
    const float* __restrict__ bias, float* __restrict__ Cf,
    _Float16* __restrict__ Ch, int M, int N, int K, int Nout)
{
    constexpr int BK = 32;
    __shared__ _Float16 sA[2][128 * BK];
    __shared__ _Float16 sB[2][128 * BK];

    const int tid = threadIdx.x;
    const int m0 = blockIdx.y * 128;
    const int n0 = blockIdx.x * 128;

    const int rA  = tid >> 2;
    const int k8  = tid & 3;
    const int swW = ((k8 ^ (rA & 3)) << 3);

    half8 rg[4];

    auto load_tile = [&](int kt) {
        const size_t koff = (size_t)kt * BK + k8 * 8;
        rg[0] = *(const half8*)(A + (size_t)(m0 + rA) * K + koff);
        rg[1] = *(const half8*)(A + (size_t)(m0 + rA + 64) * K + koff);
        half8 z;
        #pragma unroll
        for (int j = 0; j < 8; ++j) z[j] = (_Float16)0.f;
        if (EPI == 0 || (n0 + rA) < N)
            rg[2] = *(const half8*)(B + (size_t)(n0 + rA) * K + koff);
        else rg[2] = z;
        if (EPI == 0 || (n0 + rA + 64) < N)
            rg[3] = *(const half8*)(B + (size_t)(n0 + rA + 64) * K + koff);
        else rg[3] = z;
    };

    auto write_tile = [&](int buf) {
        *(half8*)&sA[buf][ rA       * BK + swW] = rg[0];
        *(half8*)&sA[buf][(rA + 64) * BK + swW] = rg[1];
        *(half8*)&sB[buf][ rA       * BK + swW] = rg[2];
        *(half8*)&sB[buf][(rA + 64) * BK + swW] = rg[3];
    };

    const int lane = tid & 63;
    const int wid  = tid >> 6;
    const int wr = wid >> 1, wc = wid & 1;
    const int fr = lane & 15, fq = lane >> 4;
    const int swR   = ((fq ^ (fr & 3)) << 3);
    const int aBase = (wr * 64 + fr) * BK + swR;
    const int bBase = (wc * 64 + fr) * BK + swR;

    f32x4 acc[4][4];
    #pragma unroll
    for (int i = 0; i < 4; ++i)
        #pragma unroll
        for (int j = 0; j < 4; ++j) acc[i][j] = (f32x4)(0.f);

    const int NT = K / BK;
    load_tile(0);
    write_tile(0);
    int cur = 0;

    for (int kt = 0; kt < NT; ++kt) {
        const bool more = (kt + 1 < NT);
        if (more) load_tile(kt + 1);
        __syncthreads();

        half8 a_[4], b_[4];
        #pragma unroll
        for (int f = 0; f < 4; ++f) {
            a_[f] = *(const half8*)&sA[cur][aBase + f * 16 * BK];
            b_[f] = *(const half8*)&sB[cur][bBase + f * 16 * BK];
        }
        #pragma unroll
        for (int fm = 0; fm < 4; ++fm)
            #pragma unroll
            for (int fn = 0; fn < 4; ++fn)
                acc[fm][fn] = __builtin_amdgcn_mfma_f32_16x16x32_f16(
                    a_[fm], b_[fn], acc[fm][fn], 0, 0, 0);

        if (more) write_tile(cur ^ 1);
        cur ^= 1;
    }

    if (EPI == 0) {
        #pragma unroll
        for (int fn = 0; fn < 4; ++fn) {
            const int col = n0 + wc * 64 + fn * 16 + fr;
            const float bv = bias[col];
            #pragma unroll
            for (int fm = 0; fm < 4; ++fm) {
                const int row0 = m0 + wr * 64 + fm * 16 + fq * 4;
                #pragma unroll
                for (int r = 0; r < 4; ++r)
                    Ch[(size_t)(row0 + r) * Nout + col] =
                        (_Float16)fmaxf(acc[fm][fn][r] + bv, 0.f);
            }
        }
    } else {
        #pragma unroll
        for (int fn = 0; fn < 4; ++fn) {
            const int col = n0 + wc * 64 + fn * 16 + fr;
            if (col < Nout) {
                const float bv = bias[col];
                #pragma unroll
                for (int fm = 0; fm < 4; ++fm) {
                    const int row0 = m0 + wr * 64 + fm * 16 + fq * 4;
                    #pragma unroll
                    for (int r = 0; r < 4; ++r)
                        Cf[(size_t)(row0 + r) * Nout + col] = acc[fm][fn][r] + bv;
                }
            }
        }
    }
}

// ---------------------------------------------------------------------------
// Rotate — chunked chains + MFMA tree (structure = passing R15), cs packed
// as f16 pairs. One ds_read_b128 (half8) = 4 (c,s) pairs = 4 rotations ->
// 31 reads per 124-rotation chain (R15: 62). [R16 bug: treated a half8 as
// 8 pairs -> hv[8..15] OOB -> NaN. Fixed: group = 4 rotations, I=0..3.]
//   cs layout: [2 batches][4 chunks x 128 slots] x (c,s) f16; chunk padded
//   124->128. ODD chunks store slots reversed (slot s = rotation 123-s) so
//   column chains read forward-aligned.
//   Tree (verified R15): L1 pi=0: mfma(C1^T,C0)=P0^T -> col-major => P0 rows;
//   pi=1: mfma(C2,C3^T)=P1 -> col-major => P1^T rows. L2: mfma(P1^T,P0) =
//   P1^T@P0^T = R^T; lane = 4 consecutive cols of R -> b128 stores.
// LDS 24KB: cs [0,4KB) f16 (-> PCM after chains); EVEN [8,16)KB (-> R f32
// after L1); ODD [16,24)KB.
// ---------------------------------------------------------------------------
struct IJTbl { unsigned char i[NANG]; unsigned char j[NANG]; };
constexpr IJTbl make_ij_tbl() {
    IJTbl t{};
    int k = 0;
    for (int i = 0; i < NROT - 1; ++i)
        for (int j = i + 1; j < NROT; ++j) { t.i[k] = (unsigned char)i; t.j[k] = (unsigned char)j; ++k; }
    return t;
}
constexpr IJTbl IJT = make_ij_tbl();

#define CS_H   0       // f16 idx: cs pairs, 2 x 512 slots x 2 f16 = [0,2048)
#define PCM_H  0       // f16 idx: P region overlays cs after chains, [0,4096)
#define EVEN_H 4096    // f16 idx: even factors (= f32 2048)
#define ODD_H  8192    // f16 idx: odd factors  (= f32 4096)
#define RF32   2048    // f32 idx: R output overlays EVEN after L1

template<int K, bool REV>
__device__ __forceinline__ void rot1(float c, float s, float (&v)[NROT]) {
    constexpr int i = IJT.i[K], j = IJT.j[K];
    const float vi = v[i], vj = v[j];
    if constexpr (!REV) {
        v[i] = fmaf(c, vi,  s * vj);
        v[j] = fmaf(c, vj, -s * vi);
    } else {
        v[i] = fmaf(c, vi, -s * vj);
        v[j] = fmaf(c, vj,  s * vi);
    }
}

template<int W, int G, int I>   // slot s = 4G+I (0..123), pair at hv[2I],hv[2I+1]
__device__ __forceinline__ void rot_elem(const half8 hv, float (&v)[NROT]) {
    const float c = (float)hv[2 * I];
    const float s = (float)hv[2 * I + 1];
    if constexpr ((W & 1) == 0)
        rot1<124 * W + 4 * G + I, false>(c, s, v);
    else
        rot1<124 * W + 123 - (4 * G + I), true>(c, s, v);
}

template<int W, int G>   // G = 0..30: one half8 = slots 4G..4G+3 = 4 rotations
__device__ __forceinline__ void chain_g(const _Float16* __restrict__ lcsh,
                                        float (&v)[NROT]) {
    const half8 hv = *(const half8*)&lcsh[W * 256 + G * 8];
    rot_elem<W, G, 0>(hv, v);
    rot_elem<W, G, 1>(hv, v);
    rot_elem<W, G, 2>(hv, v);
    rot_elem<W, G, 3>(hv, v);
}

template<int W, size_t... Gs>
__device__ __forceinline__ void chain_runW(const _Float16* __restrict__ lcsh,
                                           float (&v)[NROT],
                                           std::index_sequence<Gs...>) {
    (chain_g<W, (int)Gs>(lcsh, v), ...);
}

template<int W>
__device__ __forceinline__ void chain_and_store(const _Float16* __restrict__ lcsh,
                                                _Float16* __restrict__ lh,
                                                int half, int r) {
    float v[NROT];
    #pragma unroll
    for (int c = 0; c < NROT; ++c) v[c] = (c == r) ? 1.f : 0.f;
    chain_runW<W>(lcsh, v, std::make_index_sequence<31>{});   // 31 x 4 = 124

    // even: row r of C; odd: row r of C^T — identical vectorized store.
    constexpr int REG = ((W & 1) == 0) ? EVEN_H : ODD_H;
    const int base = REG + (half * 2 + (W >> 1)) * 1024;
    #pragma unroll
    for (int kq = 0; kq < 4; ++kq) {
        half8 hv;
        #pragma unroll
        for (int j = 0; j < 8; ++j) hv[j] = (_Float16)v[kq * 8 + j];
        *(half8*)&lh[base + r * 32 + ((kq ^ (r & 3)) << 3)] = hv;
    }
}

__global__ __launch_bounds__(256) void rotate_kernel(
    const float* __restrict__ theta, float* __restrict__ out)
{
    __shared__ float smem[6144];   // 24 KB
    _Float16* lh = (_Float16*)smem;

    const int tid  = threadIdx.x;
    const int wid  = tid >> 6;
    const int lane = tid & 63;
    const int half = (tid >> 5) & 1;       // batch within block (chain phase)
    const int r    = tid & 31;             // row / column index
    const int fr = lane & 15, fq = lane >> 4;
    const size_t b0 = (size_t)blockIdx.x * 2;

    // ---- stage: theta -> sincos -> f16 (c,s) pairs, odd chunks reversed ----
    {
        const int m = tid & 31;            // slot group 0..30 (31 idle)
        const int w = (tid >> 5) & 3;      // chunk
        const int b = tid >> 7;            // batch
        if (m < 31) {
            const int rot0 = 124 * w + ((w & 1) ? (120 - 4 * m) : (4 * m));
            const f32x4 th = *(const f32x4*)(theta + (b0 + b) * NANG + rot0);
            half8 hv;
            #pragma unroll
            for (int i2 = 0; i2 < 4; ++i2) {
                const float ang = (w & 1) ? th[3 - i2] : th[i2];
                float s, c;
                __sincosf(ang, &s, &c);
                hv[2 * i2]     = (_Float16)c;
                hv[2 * i2 + 1] = (_Float16)s;
            }
            *(half8*)&lh[CS_H + (b * 512 + w * 128 + m * 4) * 2] = hv;
        }
    }
    __syncthreads();

    // ---- chunk chains (wave-uniform branch) ----
    const _Float16* lcsh = lh + CS_H + half * 1024;
    if      (wid == 0) chain_and_store<0>(lcsh, lh, half, r);
    else if (wid == 1) chain_and_store<1>(lcsh, lh, half, r);
    else if (wid == 2) chain_and_store<2>(lcsh, lh, half, r);
    else               chain_and_store<3>(lcsh, lh, half, r);
    __syncthreads();

    // ---- L1: wave (ba,pi) ----
    //  pi=0: D = mfma(C1^T, C0)  = P0^T  -> col-major store => PCM0 = P0 rows
    //  pi=1: D = mfma(C2, C3^T)  = P1    -> col-major store => PCM1 = P1^T rows
    {
        const int ba = wid >> 1, pi = wid & 1;
        const int Eb = EVEN_H + (ba * 2 + pi) * 1024;   // C_{2pi} rows
        const int Ob = ODD_H  + (ba * 2 + pi) * 1024;   // C_{2pi+1}^T rows
        const int Asrc = (pi == 0) ? Ob : Eb;
        const int Bsrc = (pi == 0) ? Eb : Ob;
        const int swz = (fq ^ (fr & 3)) << 3;
        half8 a[2], b[2];
        #pragma unroll
        for (int mi = 0; mi < 2; ++mi) {
            a[mi] = *(const half8*)&lh[Asrc + (mi * 16 + fr) * 32 + swz];
            b[mi] = *(const half8*)&lh[Bsrc + (mi * 16 + fr) * 32 + swz];
        }
        const int Pb = PCM_H + (ba * 2 + pi) * 1024;
        #pragma unroll
        for (int mi = 0; mi < 2; ++mi)
            #pragma unroll
            for (int ni = 0; ni < 2; ++ni) {
                const f32x4 d = __builtin_amdgcn_mfma_f32_16x16x32_f16(
                    a[mi], b[ni], (f32x4)(0.f), 0, 0, 0);
                half4 hv;
                #pragma unroll
                for (int q = 0; q < 4; ++q) hv[q] = (_Float16)d[q];
                const int col  = ni * 16 + fr;
                const int rowb = (mi * 16 + fq * 4) ^ ((col & 3) << 3);
                *(half4*)&lh[Pb + col * 32 + rowb] = hv;
            }
    }
    __syncthreads();

    // ---- L2: D = mfma(PCM1, PCM0) = P1^T @ P0^T = R^T; lane holds 4
    //      consecutive COLUMNS of R at fixed row -> b128 stores.
    {
        const int ba = wid >> 1, mi = wid & 1;
        const int Ab = PCM_H + (ba * 2 + 1) * 1024;   // P1^T rows
        const int Bb = PCM_H + (ba * 2 + 0) * 1024;   // P0 rows
        const int swz = (fq ^ (fr & 3)) << 3;
        const half8 a = *(const half8*)&lh[Ab + (mi * 16 + fr) * 32 + swz];
        #pragma unroll
        for (int ni = 0; ni < 2; ++ni) {
            const half8 b = *(const half8*)&lh[Bb + (ni * 16 + fr) * 32 + swz];
            const f32x4 d = __builtin_amdgcn_mfma_f32_16x16x32_f16(
                a, b, (f32x4)(0.f), 0, 0, 0);
            const int row  = ni * 16 + fr;            // row of R
            const int colq = mi * 4 + fq;             // col block (4 f32)
            *(f32x4*)&smem[RF32 + ba * 1024 + row * 32 + ((colq ^ (row & 7)) << 2)] = d;
        }
    }
    __syncthreads();

    // ---- coalesced copy-out ----
    #pragma unroll
    for (int s = 0; s < 2; ++s) {
        const int idx = s * 256 + tid;
        const int ba  = idx >> 8;
        const int f4i = idx & 255;
        const int row = f4i >> 3;
        const int cc  = f4i & 7;
        const f32x4 val =
            *(const f32x4*)&smem[RF32 + ba * 1024 + row * 32 + ((cc ^ (row & 7)) << 2)];
        *(f32x4*)(out + (b0 + ba) * 1024 + (size_t)f4i * 4) = val;
    }
}

// ---------------------------------------------------------------------------
extern "C" void kernel_launch(void* const* d_in, const int* in_sizes, int n_in,
                              void* d_out, int out_size, void* d_ws, size_t ws_size,
                              hipStream_t stream)
{
    const float* x  = (const float*)d_in[0];   // [16384, 512]
    const float* W1 = (const float*)d_in[1];   // [1024, 512]
    const float* b1 = (const float*)d_in[2];   // [1024]
    const float* W2 = (const float*)d_in[3];   // [496, 1024]
    const float* b2 = (const float*)d_in[4];   // [496]
    float* out = (float*)d_out;                // [16384, 32, 32]

    // d_out (67.1 MB) doubles as f16 scratch; rotate rewrites all of it last.
    _Float16* h16  = (_Float16*)d_out;               // 33.55 MB
    _Float16* x16  = h16  + (size_t)BATCH * HIDDEN;  // 16.78 MB
    _Float16* W116 = x16  + (size_t)BATCH * INPUT_DIM;
    _Float16* W216 = W116 + (size_t)HIDDEN * INPUT_DIM;
    float*    th   = (float*)d_ws;                   // theta [16384][496] f32

    cvt_f32_f16<<<dim3((BATCH * INPUT_DIM / 8 + 255) / 256), 256, 0, stream>>>(
        x, x16, BATCH * INPUT_DIM / 8);
    cvt_f32_f16<<<dim3((HIDDEN * INPUT_DIM / 8 + 255) / 256), 256, 0, stream>>>(
        W1, W116, HIDDEN * INPUT_DIM / 8);
    cvt_f32_f16<<<dim3((NANG * HIDDEN / 8 + 255) / 256), 256, 0, stream>>>(
        W2, W216, NANG * HIDDEN / 8);

    gemm_nt_f16<0><<<dim3(HIDDEN / 128, BATCH / 128), 256, 0, stream>>>(
        x16, W116, b1, nullptr, h16, BATCH, HIDDEN, INPUT_DIM, HIDDEN);

    gemm_nt_f16<1><<<dim3((NANG + 127) / 128, BATCH / 128), 256, 0, stream>>>(
        h16, W216, b2, th, nullptr, BATCH, NANG, HIDDEN, NANG);

    rotate_kernel<<<dim3(BATCH / 2), 256, 0, stream>>>(th, out);
}